// Round 8
// baseline (229.438 us; speedup 1.0000x reference)
//
#include <hip/hip_runtime.h>
#include <hip/hip_bf16.h>
#include <math.h>

// Shapes (fixed by setup_inputs): B=8, n=32, C=64, O=64
#define NB 8
#define NN 32
#define NC 64
#define NO 64

// ---- workspace layout (float offsets). end = 1,242,880 floats = 4.97 MB ----
#define WS_G    0         // 4: gate for o0..o3
#define WS_MF   16        // 80: act as float
#define WS_R1   128       // 1024 f32: reduce(x1,1) interleaved
#define WS_X1B  36864     // 16384 ushort: x1 as bf16
#define WS_X2B  45056     // 524288 ushort: x2 as bf16
#define WS_R3B  307200    // 1048576 ushort: reduce(x3,3) bf16 interleaved (128/slot)
#define WS_BB   831488    // 512 f32: per-b o3 bias
#define WS_BB2  832000    // 512 f32: per-b o2 bias
#define WS_WC   832512    // 393216 ushort: o3 weights, frag-ordered [b][nt][kk24][lane][8]
#define WS_WC2  1029120   // 262144 ushort: o2 weights, frag-ordered [b][nt][kk16][lane][8]
#define WS_R2B  1160192   // 32768 ushort: reduce(x2,2) bf16 interleaved (128/slot)
#define WS_WC1  1176576   // 131072 ushort: o1 weights, frag-ordered [b][nt][kk8][lane][8]
#define WS_X0B  1242112   // 512 ushort: x0 as bf16
#define WS_BB1  1242368   // 512 f32: per-b o1 bias
// end = 1242880

typedef short bf16x8 __attribute__((ext_vector_type(8)));
typedef unsigned short u16x4 __attribute__((ext_vector_type(4)));
typedef float f32x4 __attribute__((ext_vector_type(4)));

__device__ __forceinline__ float sigmoidf_(float s) {
    return 1.0f / (1.0f + expf(-s));
}

__device__ __forceinline__ unsigned short f2b(float x) {
    union { __hip_bfloat16 h; unsigned short u; } v;
    v.h = __float2bfloat16(x);   // RNE; pairs into v_cvt_pk_bf16_f32
    return v.u;
}

__device__ __forceinline__ float b2f(unsigned short u) {
    union { unsigned int u; float f; } v; v.u = ((unsigned int)u) << 16;
    return v.f;
}

// ---- prep (fused): combined weights + gates/masks/biases/x0b + red1 + red2 ----
__global__ __launch_bounds__(256) void prep_all(
        const float* __restrict__ x0, const float* __restrict__ x1,
        const float* __restrict__ x2,
        const float* __restrict__ we3, const float* __restrict__ wo3,
        const float* __restrict__ we2, const float* __restrict__ wo2,
        const float* __restrict__ wr2,
        const float* __restrict__ we1, const float* __restrict__ wo1,
        const float* __restrict__ wr1,
        const float* __restrict__ be1, const float* __restrict__ bo1,
        const float* __restrict__ br1,
        const float* __restrict__ be2, const float* __restrict__ bo2,
        const float* __restrict__ br2,
        const float* __restrict__ be3, const float* __restrict__ bo3,
        const int* __restrict__ act, float* __restrict__ ws) {
    __shared__ float pmx[4][64], pmn[4][64];
    int bb = blockIdx.x, t = threadIdx.x;
    if (bb < 1536) {
        int tid = bb * 256 + t;
        unsigned short* wc = (unsigned short*)(ws + WS_WC);
        int i8 = tid & 7;
        int lane = (tid >> 3) & 63;
        int rest = tid >> 9;          // 0..767
        int kk = rest % 24;
        int ntb = rest / 24;
        int nt = ntb & 3, b = ntb >> 2;
        int o = nt * 16 + (lane & 15);
        int kloc = kk * 32 + ((lane >> 4) << 3) + i8;
        bool m8 = act[b * 10 + 8] == 1;
        bool m9 = act[b * 10 + 9] == 1;
        float val;
        if (kloc < 384) val = m8 ? we3[o * 384 + kloc] : 0.0f;
        else            val = m9 ? wo3[o * 384 + kloc - 384] : 0.0f;
        wc[tid] = f2b(val);
    } else if (bb < 2560) {
        int tid = (bb - 1536) * 256 + t;
        unsigned short* wc2 = (unsigned short*)(ws + WS_WC2);
        int i8 = tid & 7;
        int lane = (tid >> 3) & 63;
        int rest = tid >> 9;          // 0..511
        int kk = rest & 15;
        int ntb = rest >> 4;
        int nt = ntb & 3, b = ntb >> 2;
        int o = nt * 16 + (lane & 15);
        int kloc = kk * 32 + ((lane >> 4) << 3) + i8;
        float val;
        if (kloc < 128)      val = (act[b * 10 + 5] == 1) ? we2[o * 128 + kloc] : 0.0f;
        else if (kloc < 256) val = (act[b * 10 + 6] == 1) ? wo2[o * 128 + kloc - 128] : 0.0f;
        else                 val = (act[b * 10 + 7] == 1) ? wr2[o * 256 + kloc - 256] : 0.0f;
        wc2[tid] = f2b(val);
    } else if (bb < 3072) {
        int tid = (bb - 2560) * 256 + t;
        unsigned short* wc1 = (unsigned short*)(ws + WS_WC1);
        int i8 = tid & 7;
        int lane = (tid >> 3) & 63;
        int rest = tid >> 9;          // 0..255
        int kk = rest & 7;
        int ntb = rest >> 3;
        int nt = ntb & 3, b = ntb >> 2;
        int o = nt * 16 + (lane & 15);
        int kloc = kk * 32 + ((lane >> 4) << 3) + i8;
        float val;
        if (kloc < 64)       val = (act[b * 10 + 2] == 1) ? we1[o * 64 + kloc] : 0.0f;
        else if (kloc < 128) val = (act[b * 10 + 3] == 1) ? wo1[o * 64 + kloc - 64] : 0.0f;
        else                 val = (act[b * 10 + 4] == 1) ? wr1[o * 128 + kloc - 128] : 0.0f;
        wc1[tid] = f2b(val);
    } else if (bb < 3074) {
        int t512 = (bb - 3072) * 256 + t;   // 0..511
        int b = t512 >> 6, o = t512 & 63;
        float m2 = (act[b * 10 + 2] == 1) ? 1.0f : 0.0f;
        float m3 = (act[b * 10 + 3] == 1) ? 1.0f : 0.0f;
        float m4 = (act[b * 10 + 4] == 1) ? 1.0f : 0.0f;
        float m5 = (act[b * 10 + 5] == 1) ? 1.0f : 0.0f;
        float m6 = (act[b * 10 + 6] == 1) ? 1.0f : 0.0f;
        float m7 = (act[b * 10 + 7] == 1) ? 1.0f : 0.0f;
        float m8 = (act[b * 10 + 8] == 1) ? 1.0f : 0.0f;
        float m9 = (act[b * 10 + 9] == 1) ? 1.0f : 0.0f;
        ws[WS_BB1 + t512] = m2 * be1[o] + m3 * bo1[o] + m4 * br1[o];
        ws[WS_BB2 + t512] = m5 * be2[o] + m6 * bo2[o] + m7 * br2[o];
        ws[WS_BB  + t512] = m8 * be3[o] + m9 * bo3[o];
        unsigned short* x0b = (unsigned short*)(ws + WS_X0B);
        x0b[t512] = f2b(x0[t512]);
        if (t512 < 80) ws[WS_MF + t512] = (act[t512] == 1) ? 1.0f : 0.0f;
        if (t512 < 4) {
            const int lo[4] = {0, 2, 5, 8};
            const int hi[4] = {2, 5, 8, 10};
            int any = 0;
            for (int bx = 0; bx < NB; ++bx)
                for (int bit = lo[t512]; bit < hi[t512]; ++bit)
                    any |= (act[bx * 10 + bit] == 1);
            ws[WS_G + t512] = any ? 1.0f : 0.0f;
        }
    } else if (bb < 3082) {
        // red1: x1 -> bf16 + interleaved f32 max/min (for out0)
        if (t < 64) {
            int b = bb - 3074, c = t;
            unsigned short* x1b = (unsigned short*)(ws + WS_X1B);
            float mx = -INFINITY, mn = INFINITY;
            for (int k = 0; k < NN; ++k) {
                float v = x1[(b * NN + k) * NC + c];
                x1b[(b * NN + k) * NC + c] = f2b(v);
                mx = fmaxf(mx, v); mn = fminf(mn, v);
            }
            ws[WS_R1 + b * 2 * NC + 2 * c]     = mx;
            ws[WS_R1 + b * 2 * NC + 2 * c + 1] = mn;
        }
    } else {
        // red2: x2 -> bf16 + r2b (bf16 interleaved), 4 waves per (b,i)
        int idx = bb - 3082;
        int i = idx & 31, b = idx >> 5;
        int w = t >> 6, c = t & 63;
        unsigned short* x2b = (unsigned short*)(ws + WS_X2B);
        float mx = -INFINITY, mn = INFINITY;
        #pragma unroll
        for (int q = 0; q < 8; ++q) {
            int jj = w * 8 + q;
            float v = x2[((b * NN + i) * NN + jj) * NC + c];
            x2b[((b * NN + i) * NN + jj) * NC + c] = f2b(v);
            mx = fmaxf(mx, (jj == i) ? 0.0f : v);
            mn = fminf(mn, (jj == i) ? 1.0f : v);
        }
        pmx[w][c] = mx; pmn[w][c] = mn;
        __syncthreads();
        if (t < 64) {
            mx = fmaxf(fmaxf(pmx[0][c], pmx[1][c]), fmaxf(pmx[2][c], pmx[3][c]));
            mn = fminf(fminf(pmn[0][c], pmn[1][c]), fminf(pmn[2][c], pmn[3][c]));
            unsigned short* r2b = (unsigned short*)(ws + WS_R2B);
            unsigned int packed = (unsigned int)f2b(mx) | ((unsigned int)f2b(mn) << 16);
            *(unsigned int*)(r2b + (b * NN + i) * 128 + 2 * c) = packed;
        }
    }
}

// ---- o3 via MFMA, PAIRED, 8 waves: block = (b = blk&7 [XCD-affine], pi = blk>>3).
// wave wv = nt (0..3) x mh (0..1): n-tile nt, m-half mh. Per wave: 24 A-frag reads,
// 48 MFMAs (2 accs: ij-output and ji-output via involution P1).
// A[32 k][768 K] bf16 LDS, XOR-swizzled (48 KB) -> 3 blocks/CU = 24 waves/CU.
// Fused r3b: wave0 from chunk6 -> (i,j); wave4 from chunk8 -> (j,i).
__global__ __launch_bounds__(512) void out3k_pair(
        const float* __restrict__ x3, const float* __restrict__ ws_f,
        float* __restrict__ out) {
    __shared__ unsigned short A[32 * 768];   // 48 KB
    int blk = blockIdx.x;
    int b = blk & 7, pi = blk >> 3;   // XCD-affine: each XCD owns one batch b
    // triangular decode: largest i with C(i)=i*(65-i)/2 <= pi
    float fsq = sqrtf(4225.0f - 8.0f * (float)pi);
    int i = (int)((65.0f - fsq) * 0.5f);
    while (i > 0 && (i * (65 - i)) / 2 > pi) --i;
    while (((i + 1) * (64 - i)) / 2 <= pi) ++i;
    int j = i + (pi - (i * (65 - i)) / 2);

    int t = threadIdx.x;
    int lane = t & 63, wv = t >> 6;
    int nt = wv & 3, mh = wv >> 2;
    const unsigned short* x2b = (const unsigned short*)(ws_f + WS_X2B);
    const unsigned short* wc = (const unsigned short*)(ws_f + WS_WC);
    char* Ab = (char*)A;

    // ---- stage 12 tiles across all 512 threads ----
    {
        // x2b chunks: t<256 -> chunks 0-2, t>=256 -> chunks 3-5; 32 rows x 8 colgrps
        int r8 = (t >> 3) & 31, c8 = (t & 7) << 3;
        int cset = (t >> 8) * 3;
        size_t cb[6]; int cs[6];
        cb[0] = ((b * 32 + i) * 32 + j) * 64; cs[0] = 0;
        cb[1] = ((b * 32 + i) * 32) * 64;     cs[1] = 64;
        cb[2] = ((b * 32 + j) * 32 + i) * 64; cs[2] = 0;
        cb[3] = (b * 1024 + i) * 64;          cs[3] = 2048;
        cb[4] = ((b * 32 + j) * 32) * 64;     cs[4] = 64;
        cb[5] = (b * 1024 + j) * 64;          cs[5] = 2048;
        int sw = (r8 & 7) << 4;
        #pragma unroll
        for (int cc = 0; cc < 3; ++cc) {
            int ch = cset + cc;
            bf16x8 v = *(const bf16x8*)(x2b + cb[ch] + (size_t)r8 * cs[ch] + c8);
            *(bf16x8*)(Ab + ((r8 * 1536 + (ch * 64 + c8) * 2) ^ sw)) = v;
        }
        // x3 chunks: 32 rows (t>>4) x 16 colgrps (f32x4); each thread all 6 chunks
        int r32 = t >> 4, c4 = (t & 15) << 2;
        const float* xb[6]; int xs[6];
        xb[0] = x3 + (size_t)(((b * 32 + i) * 32 + j) * 32) * 64; xs[0] = 64;
        xb[1] = x3 + (size_t)(((b * 32 + i) * 32) * 32 + j) * 64; xs[1] = 2048;
        xb[2] = x3 + (size_t)(((b * 32 + j) * 32 + i) * 32) * 64; xs[2] = 64;
        xb[3] = x3 + (size_t)((b * 1024 + i) * 32 + j) * 64;      xs[3] = 65536;
        xb[4] = x3 + (size_t)(((b * 32 + j) * 32) * 32 + i) * 64; xs[4] = 2048;
        xb[5] = x3 + (size_t)(b * 32768 + j * 32 + i) * 64;       xs[5] = 65536;
        int sw2 = (r32 & 7) << 4;
        #pragma unroll
        for (int ch = 0; ch < 6; ++ch) {
            f32x4 v = *(const f32x4*)(xb[ch] + (size_t)r32 * xs[ch] + c4);
            u16x4 hh = { f2b(v[0]), f2b(v[1]), f2b(v[2]), f2b(v[3]) };
            *(u16x4*)(Ab + ((r32 * 1536 + ((6 + ch) * 64 + c4) * 2) ^ sw2)) = hh;
        }
    }
    __syncthreads();

    // ---- MFMA: per wave 24 A-reads feed 48 MFMAs (ij and ji accumulators) ----
    f32x4 accI = {0.f,0.f,0.f,0.f};   // (i,j) output, m-half mh
    f32x4 accJ = {0.f,0.f,0.f,0.f};   // (j,i) output, m-half mh
    const unsigned short* wblk = wc + (size_t)((b * 4 + nt) * 24) * 512 + lane * 8;
    int arow = (lane & 15) + mh * 16;
    int kgrp2 = ((lane >> 4) << 3) * 2;
    int sw0 = ((lane & 15) & 7) << 4;   // (arow & 7) == ((lane&15) & 7) since mh*16 keeps low 3 bits
    const int P1[12] = {2, 4, 0, 5, 1, 3, 8, 10, 6, 11, 7, 9};
    #pragma unroll
    for (int c = 0; c < 12; ++c) {
        #pragma unroll
        for (int s = 0; s < 2; ++s) {
            int colb = c * 128 + s * 64 + kgrp2;
            bf16x8 a = *(const bf16x8*)(Ab + ((arow * 1536 + colb) ^ sw0));
            bf16x8 w0 = *(const bf16x8*)(wblk + (2 * c + s) * 512);
            bf16x8 w1 = *(const bf16x8*)(wblk + (2 * P1[c] + s) * 512);
            accI = __builtin_amdgcn_mfma_f32_16x16x32_bf16(a, w0, accI, 0, 0, 0);
            accJ = __builtin_amdgcn_mfma_f32_16x16x32_bf16(a, w1, accJ, 0, 0, 0);
        }
    }

    // ---- fused r3b: wave0 from chunk6 -> (i,j); wave4 from chunk8 -> (j,i) ----
    if (wv == 0 || (wv == 4 && i != j)) {
        int c = lane;
        int colbase = (wv == 0) ? 384 : 512;   // chunk 6 / chunk 8 column base
        float mx = 0.0f, mn = 1.0f;            // masked entries contribute 0 / 1
        if (i != j) {
            for (int k = 0; k < 32; ++k) {
                if (k == i || k == j) continue;
                int addr = (k * 1536 + (colbase + c) * 2) ^ ((k & 7) << 4);
                float v = b2f(*(const unsigned short*)(Ab + addr));
                mx = fmaxf(mx, v); mn = fminf(mn, v);
            }
        }
        unsigned short* r3b = (unsigned short*)(ws_f + WS_R3B);
        int slot = (wv == 0) ? ((b * 32 + i) * 32 + j) : ((b * 32 + j) * 32 + i);
        unsigned int packed = (unsigned int)f2b(mx) | ((unsigned int)f2b(mn) << 16);
        *(unsigned int*)(r3b + (size_t)slot * 128 + 2 * c) = packed;
    }

    // ---- epilogue: rows mh*16 + (lane>>4)*4 + r ----
    float g3 = ws_f[WS_G + 3];
    int o = nt * 16 + (lane & 15);
    float bias = ws_f[WS_BB + b * 64 + o];
    int row0 = mh * 16 + ((lane >> 4) << 2);
    float* ob0 = out + (size_t)(((b * 32 + i) * 32 + j) * 32) * 64;
    float* ob1 = out + (size_t)(((b * 32 + j) * 32 + i) * 32) * 64;
    #pragma unroll
    for (int r = 0; r < 4; ++r) {
        float s0 = accI[r] + bias;
        ob0[(row0 + r) * 64 + o] = (g3 != 0.0f) ? sigmoidf_(s0) : 0.0f;
    }
    if (i != j) {
        #pragma unroll
        for (int r = 0; r < 4; ++r) {
            float s1 = accJ[r] + bias;
            ob1[(row0 + r) * 64 + o] = (g3 != 0.0f) ? sigmoidf_(s1) : 0.0f;
        }
    }
}

// ---- o0 + o1 fused: blocks 0..7 = o0 (t<64); blocks 8..15 = o1 MFMA ----
__global__ __launch_bounds__(256) void out01(
        const float* __restrict__ x0,
        const float* __restrict__ w_op0, const float* __restrict__ b_op0,
        const float* __restrict__ w_red0, const float* __restrict__ b_red0,
        const float* __restrict__ ws_f, float* __restrict__ out0,
        float* __restrict__ out1) {
    __shared__ unsigned short A[32 * 256];   // 16 KB (o1 path only)
    int bb = blockIdx.x, t = threadIdx.x;
    if (bb < 8) {
        if (t >= 64) return;
        int b = bb, o = t;
        float g  = ws_f[WS_G + 0];
        float m0 = ws_f[WS_MF + b * 10 + 0], m1 = ws_f[WS_MF + b * 10 + 1];
        float d0 = b_op0[o];
        for (int c = 0; c < NC; ++c) d0 += w_op0[o * NC + c] * x0[b * NC + c];
        float d1 = b_red0[o];
        for (int c = 0; c < 2 * NC; ++c) d1 += w_red0[o * 2 * NC + c] * ws_f[WS_R1 + b * 2 * NC + c];
        float s = m0 * d0 + m1 * d1;
        out0[b * NO + o] = (g != 0.0f) ? sigmoidf_(s) : 0.0f;
        return;
    }
    int b = bb - 8;
    int lane = t & 63, nt = t >> 6;
    const unsigned short* x0b = (const unsigned short*)(ws_f + WS_X0B);
    const unsigned short* x1b = (const unsigned short*)(ws_f + WS_X1B);
    const unsigned short* r2b = (const unsigned short*)(ws_f + WS_R2B);
    const unsigned short* wc1 = (const unsigned short*)(ws_f + WS_WC1);
    char* Ab = (char*)A;
    int r = t >> 3, c8 = (t & 7) << 3;
    int sw = (r & 7) << 4;
    {
        bf16x8 v0 = *(const bf16x8*)(x0b + b * 64 + c8);
        bf16x8 v1 = *(const bf16x8*)(x1b + (b * 32 + r) * 64 + c8);
        bf16x8 v2 = *(const bf16x8*)(r2b + (b * 32 + r) * 128 + c8);
        bf16x8 v3 = *(const bf16x8*)(r2b + (b * 32 + r) * 128 + 64 + c8);
        *(bf16x8*)(Ab + ((r * 512 + (0 * 64 + c8) * 2) ^ sw)) = v0;
        *(bf16x8*)(Ab + ((r * 512 + (1 * 64 + c8) * 2) ^ sw)) = v1;
        *(bf16x8*)(Ab + ((r * 512 + (2 * 64 + c8) * 2) ^ sw)) = v2;
        *(bf16x8*)(Ab + ((r * 512 + (3 * 64 + c8) * 2) ^ sw)) = v3;
    }
    __syncthreads();
    f32x4 acc0 = {0.f,0.f,0.f,0.f};
    f32x4 acc1 = {0.f,0.f,0.f,0.f};
    const unsigned short* wblk = wc1 + (size_t)((b * 4 + nt) * 8) * 512 + lane * 8;
    int arow0 = lane & 15, arow1 = 16 + arow0;
    int kgrp2 = ((lane >> 4) << 3) * 2;
    int sw0 = (arow0 & 7) << 4;
    #pragma unroll
    for (int kk = 0; kk < 8; ++kk) {
        int kloc2 = kk * 64 + kgrp2;
        bf16x8 a0 = *(const bf16x8*)(Ab + ((arow0 * 512 + kloc2) ^ sw0));
        bf16x8 a1 = *(const bf16x8*)(Ab + ((arow1 * 512 + kloc2) ^ sw0));
        bf16x8 bw = *(const bf16x8*)(wblk + kk * 512);
        acc0 = __builtin_amdgcn_mfma_f32_16x16x32_bf16(a0, bw, acc0, 0, 0, 0);
        acc1 = __builtin_amdgcn_mfma_f32_16x16x32_bf16(a1, bw, acc1, 0, 0, 0);
    }
    float g1 = ws_f[WS_G + 1];
    int o = nt * 16 + (lane & 15);
    float bias = ws_f[WS_BB1 + b * 64 + o];
    int rgrp = (lane >> 4) << 2;
    float* obase = out1 + b * 2048;
    #pragma unroll
    for (int rr = 0; rr < 4; ++rr) {
        float s0 = acc0[rr] + bias;
        float s1 = acc1[rr] + bias;
        obase[(rgrp + rr) * 64 + o]      = (g1 != 0.0f) ? sigmoidf_(s0) : 0.0f;
        obase[(16 + rgrp + rr) * 64 + o] = (g1 != 0.0f) ? sigmoidf_(s1) : 0.0f;
    }
}

// ---- o2 via MFMA: block per (b,i); A[32 j][512 K] bf16 LDS, XOR-swizzled ----
__global__ __launch_bounds__(256) void out2k_mfma(
        const float* __restrict__ ws_f, float* __restrict__ out) {
    __shared__ unsigned short A[32 * 512];   // 32 KB
    int blk = blockIdx.x;
    int i = blk & 31, b = blk >> 5;
    int t = threadIdx.x;
    int lane = t & 63, nt = t >> 6;
    const unsigned short* x1b = (const unsigned short*)(ws_f + WS_X1B);
    const unsigned short* x2b = (const unsigned short*)(ws_f + WS_X2B);
    const unsigned short* r3b = (const unsigned short*)(ws_f + WS_R3B);
    const unsigned short* wc2 = (const unsigned short*)(ws_f + WS_WC2);
    char* Ab = (char*)A;
    int r8 = t >> 3, c8 = (t & 7) << 3;
    {
        bf16x8 v0 = *(const bf16x8*)(x1b + (b * 32 + i) * 64 + c8);
        bf16x8 v1 = *(const bf16x8*)(x1b + b * 2048 + r8 * 64 + c8);
        bf16x8 v2 = *(const bf16x8*)(x2b + ((b * 32 + i) * 32) * 64 + r8 * 64 + c8);
        bf16x8 v3 = *(const bf16x8*)(x2b + (b * 1024 + i) * 64 + r8 * 2048 + c8);
        int sw = (r8 & 7) << 4;
        *(bf16x8*)(Ab + ((r8 * 1024 + (0 * 64 + c8) * 2) ^ sw)) = v0;
        *(bf16x8*)(Ab + ((r8 * 1024 + (1 * 64 + c8) * 2) ^ sw)) = v1;
        *(bf16x8*)(Ab + ((r8 * 1024 + (2 * 64 + c8) * 2) ^ sw)) = v2;
        *(bf16x8*)(Ab + ((r8 * 1024 + (3 * 64 + c8) * 2) ^ sw)) = v3;
    }
    int r16 = t >> 4, c16 = (t & 15) << 3;
    #pragma unroll
    for (int p = 0; p < 2; ++p) {
        int jr = p * 16 + r16;
        bf16x8 v4 = *(const bf16x8*)(r3b + ((b * 32 + i) * 32 + jr) * 128 + c16);
        bf16x8 v5 = *(const bf16x8*)(r3b + ((b * 32 + jr) * 32 + i) * 128 + c16);
        int sw = (jr & 7) << 4;
        *(bf16x8*)(Ab + ((jr * 1024 + (256 + c16) * 2) ^ sw)) = v4;
        *(bf16x8*)(Ab + ((jr * 1024 + (384 + c16) * 2) ^ sw)) = v5;
    }
    __syncthreads();
    f32x4 acc0 = {0.f,0.f,0.f,0.f};
    f32x4 acc1 = {0.f,0.f,0.f,0.f};
    const unsigned short* wblk = wc2 + (size_t)((b * 4 + nt) * 16) * 512 + lane * 8;
    int arow0 = lane & 15, arow1 = 16 + arow0;
    int kgrp2 = ((lane >> 4) << 3) * 2;
    int sw0 = (arow0 & 7) << 4;
    #pragma unroll
    for (int kk = 0; kk < 16; ++kk) {
        int kloc2 = kk * 64 + kgrp2;
        bf16x8 a0 = *(const bf16x8*)(Ab + ((arow0 * 1024 + kloc2) ^ sw0));
        bf16x8 a1 = *(const bf16x8*)(Ab + ((arow1 * 1024 + kloc2) ^ sw0));
        bf16x8 bf = *(const bf16x8*)(wblk + kk * 512);
        acc0 = __builtin_amdgcn_mfma_f32_16x16x32_bf16(a0, bf, acc0, 0, 0, 0);
        acc1 = __builtin_amdgcn_mfma_f32_16x16x32_bf16(a1, bf, acc1, 0, 0, 0);
    }
    float g2 = ws_f[WS_G + 2];
    int o = nt * 16 + (lane & 15);
    float bias = ws_f[WS_BB2 + b * 64 + o];
    int rgrp = (lane >> 4) << 2;
    float* obase = out + (size_t)((b * 32 + i) * 32) * 64;
    #pragma unroll
    for (int r = 0; r < 4; ++r) {
        float s0 = acc0[r] + bias;
        float s1 = acc1[r] + bias;
        obase[(rgrp + r) * 64 + o]      = (g2 != 0.0f) ? sigmoidf_(s0) : 0.0f;
        obase[(16 + rgrp + r) * 64 + o] = (g2 != 0.0f) ? sigmoidf_(s1) : 0.0f;
    }
}

extern "C" void kernel_launch(void* const* d_in, const int* in_sizes, int n_in,
                              void* d_out, int out_size, void* d_ws, size_t ws_size,
                              hipStream_t stream) {
    const float* x0 = (const float*)d_in[0];
    const float* x1 = (const float*)d_in[1];
    const float* x2 = (const float*)d_in[2];
    const float* x3 = (const float*)d_in[3];
    const float* w_op0 = (const float*)d_in[4];   const float* b_op0 = (const float*)d_in[5];
    const float* w_red0 = (const float*)d_in[6];  const float* b_red0 = (const float*)d_in[7];
    const float* w_exp1 = (const float*)d_in[8];  const float* b_exp1 = (const float*)d_in[9];
    const float* w_op1 = (const float*)d_in[10];  const float* b_op1 = (const float*)d_in[11];
    const float* w_red1 = (const float*)d_in[12]; const float* b_red1 = (const float*)d_in[13];
    const float* w_exp2 = (const float*)d_in[14]; const float* b_exp2 = (const float*)d_in[15];
    const float* w_op2 = (const float*)d_in[16];  const float* b_op2 = (const float*)d_in[17];
    const float* w_red2 = (const float*)d_in[18]; const float* b_red2 = (const float*)d_in[19];
    const float* w_exp3 = (const float*)d_in[20]; const float* b_exp3 = (const float*)d_in[21];
    const float* w_op3 = (const float*)d_in[22];  const float* b_op3 = (const float*)d_in[23];
    const int* act = (const int*)d_in[24];

    float* ws = (float*)d_ws;   // needs ~4.97 MB
    float* out = (float*)d_out;
    float* out0 = out;               // [0, 512)
    float* out1 = out + 512;         // [512, 16896)
    float* out2 = out + 16896;       // [16896, 541184)
    float* out3 = out + 541184;      // [541184, 17318400)

    prep_all<<<3338, 256, 0, stream>>>(x0, x1, x2,
                                       w_exp3, w_op3, w_exp2, w_op2, w_red2,
                                       w_exp1, w_op1, w_red1,
                                       b_exp1, b_op1, b_red1,
                                       b_exp2, b_op2, b_red2,
                                       b_exp3, b_op3, act, ws);
    out3k_pair<<<NB * 528, 512, 0, stream>>>(x3, ws, out3);
    out01<<<16, 256, 0, stream>>>(x0, w_op0, b_op0, w_red0, b_red0, ws, out0, out1);
    out2k_mfma<<<NB * NN, 256, 0, stream>>>(ws, out2);
}

// Round 9
// 227.535 us; speedup vs baseline: 1.0084x; 1.0084x over previous
//
#include <hip/hip_runtime.h>
#include <hip/hip_bf16.h>
#include <math.h>

// Shapes (fixed by setup_inputs): B=8, n=32, C=64, O=64
#define NB 8
#define NN 32
#define NC 64
#define NO 64

// ---- workspace layout (float offsets). end = 1,242,880 floats = 4.97 MB ----
#define WS_G    0         // 4: gate for o0..o3
#define WS_MF   16        // 80: act as float
#define WS_R1   128       // 1024 f32: reduce(x1,1) interleaved
#define WS_X1B  36864     // 16384 ushort: x1 as bf16
#define WS_X2B  45056     // 524288 ushort: x2 as bf16
#define WS_R3B  307200    // 1048576 ushort: reduce(x3,3) bf16 interleaved (128/slot)
#define WS_BB   831488    // 512 f32: per-b o3 bias
#define WS_BB2  832000    // 512 f32: per-b o2 bias
#define WS_WC   832512    // 393216 ushort: o3 weights, frag-ordered [b][nt][kk24][lane][8]
#define WS_WC2  1029120   // 262144 ushort: o2 weights, frag-ordered [b][nt][kk16][lane][8]
#define WS_R2B  1160192   // 32768 ushort: reduce(x2,2) bf16 interleaved (128/slot)
#define WS_WC1  1176576   // 131072 ushort: o1 weights, frag-ordered [b][nt][kk8][lane][8]
#define WS_X0B  1242112   // 512 ushort: x0 as bf16
#define WS_BB1  1242368   // 512 f32: per-b o1 bias
// end = 1242880

typedef short bf16x8 __attribute__((ext_vector_type(8)));
typedef unsigned short u16x4 __attribute__((ext_vector_type(4)));
typedef float f32x4 __attribute__((ext_vector_type(4)));

__device__ __forceinline__ float sigmoidf_(float s) {
    // fast: v_exp-based __expf + raw v_rcp_f32. |err| ~1e-6 rel, irrelevant vs 2e-2.
    return __builtin_amdgcn_rcpf(1.0f + __expf(-s));
}

__device__ __forceinline__ unsigned short f2b(float x) {
    union { __hip_bfloat16 h; unsigned short u; } v;
    v.h = __float2bfloat16(x);   // RNE; pairs into v_cvt_pk_bf16_f32
    return v.u;
}

__device__ __forceinline__ float b2f(unsigned short u) {
    union { unsigned int u; float f; } v; v.u = ((unsigned int)u) << 16;
    return v.f;
}

// ---- prep (fused): combined weights + gates/masks/biases/x0b + red1 + red2 ----
__global__ __launch_bounds__(256) void prep_all(
        const float* __restrict__ x0, const float* __restrict__ x1,
        const float* __restrict__ x2,
        const float* __restrict__ we3, const float* __restrict__ wo3,
        const float* __restrict__ we2, const float* __restrict__ wo2,
        const float* __restrict__ wr2,
        const float* __restrict__ we1, const float* __restrict__ wo1,
        const float* __restrict__ wr1,
        const float* __restrict__ be1, const float* __restrict__ bo1,
        const float* __restrict__ br1,
        const float* __restrict__ be2, const float* __restrict__ bo2,
        const float* __restrict__ br2,
        const float* __restrict__ be3, const float* __restrict__ bo3,
        const int* __restrict__ act, float* __restrict__ ws) {
    __shared__ float pmx[4][64], pmn[4][64];
    int bb = blockIdx.x, t = threadIdx.x;
    if (bb < 1536) {
        int tid = bb * 256 + t;
        unsigned short* wc = (unsigned short*)(ws + WS_WC);
        int i8 = tid & 7;
        int lane = (tid >> 3) & 63;
        int rest = tid >> 9;          // 0..767
        int kk = rest % 24;
        int ntb = rest / 24;
        int nt = ntb & 3, b = ntb >> 2;
        int o = nt * 16 + (lane & 15);
        int kloc = kk * 32 + ((lane >> 4) << 3) + i8;
        bool m8 = act[b * 10 + 8] == 1;
        bool m9 = act[b * 10 + 9] == 1;
        float val;
        if (kloc < 384) val = m8 ? we3[o * 384 + kloc] : 0.0f;
        else            val = m9 ? wo3[o * 384 + kloc - 384] : 0.0f;
        wc[tid] = f2b(val);
    } else if (bb < 2560) {
        int tid = (bb - 1536) * 256 + t;
        unsigned short* wc2 = (unsigned short*)(ws + WS_WC2);
        int i8 = tid & 7;
        int lane = (tid >> 3) & 63;
        int rest = tid >> 9;          // 0..511
        int kk = rest & 15;
        int ntb = rest >> 4;
        int nt = ntb & 3, b = ntb >> 2;
        int o = nt * 16 + (lane & 15);
        int kloc = kk * 32 + ((lane >> 4) << 3) + i8;
        float val;
        if (kloc < 128)      val = (act[b * 10 + 5] == 1) ? we2[o * 128 + kloc] : 0.0f;
        else if (kloc < 256) val = (act[b * 10 + 6] == 1) ? wo2[o * 128 + kloc - 128] : 0.0f;
        else                 val = (act[b * 10 + 7] == 1) ? wr2[o * 256 + kloc - 256] : 0.0f;
        wc2[tid] = f2b(val);
    } else if (bb < 3072) {
        int tid = (bb - 2560) * 256 + t;
        unsigned short* wc1 = (unsigned short*)(ws + WS_WC1);
        int i8 = tid & 7;
        int lane = (tid >> 3) & 63;
        int rest = tid >> 9;          // 0..255
        int kk = rest & 7;
        int ntb = rest >> 3;
        int nt = ntb & 3, b = ntb >> 2;
        int o = nt * 16 + (lane & 15);
        int kloc = kk * 32 + ((lane >> 4) << 3) + i8;
        float val;
        if (kloc < 64)       val = (act[b * 10 + 2] == 1) ? we1[o * 64 + kloc] : 0.0f;
        else if (kloc < 128) val = (act[b * 10 + 3] == 1) ? wo1[o * 64 + kloc - 64] : 0.0f;
        else                 val = (act[b * 10 + 4] == 1) ? wr1[o * 128 + kloc - 128] : 0.0f;
        wc1[tid] = f2b(val);
    } else if (bb < 3074) {
        int t512 = (bb - 3072) * 256 + t;   // 0..511
        int b = t512 >> 6, o = t512 & 63;
        float m2 = (act[b * 10 + 2] == 1) ? 1.0f : 0.0f;
        float m3 = (act[b * 10 + 3] == 1) ? 1.0f : 0.0f;
        float m4 = (act[b * 10 + 4] == 1) ? 1.0f : 0.0f;
        float m5 = (act[b * 10 + 5] == 1) ? 1.0f : 0.0f;
        float m6 = (act[b * 10 + 6] == 1) ? 1.0f : 0.0f;
        float m7 = (act[b * 10 + 7] == 1) ? 1.0f : 0.0f;
        float m8 = (act[b * 10 + 8] == 1) ? 1.0f : 0.0f;
        float m9 = (act[b * 10 + 9] == 1) ? 1.0f : 0.0f;
        ws[WS_BB1 + t512] = m2 * be1[o] + m3 * bo1[o] + m4 * br1[o];
        ws[WS_BB2 + t512] = m5 * be2[o] + m6 * bo2[o] + m7 * br2[o];
        ws[WS_BB  + t512] = m8 * be3[o] + m9 * bo3[o];
        unsigned short* x0b = (unsigned short*)(ws + WS_X0B);
        x0b[t512] = f2b(x0[t512]);
        if (t512 < 80) ws[WS_MF + t512] = (act[t512] == 1) ? 1.0f : 0.0f;
        if (t512 < 4) {
            const int lo[4] = {0, 2, 5, 8};
            const int hi[4] = {2, 5, 8, 10};
            int any = 0;
            for (int bx = 0; bx < NB; ++bx)
                for (int bit = lo[t512]; bit < hi[t512]; ++bit)
                    any |= (act[bx * 10 + bit] == 1);
            ws[WS_G + t512] = any ? 1.0f : 0.0f;
        }
    } else if (bb < 3082) {
        // red1: x1 -> bf16 + interleaved f32 max/min (for out0)
        if (t < 64) {
            int b = bb - 3074, c = t;
            unsigned short* x1b = (unsigned short*)(ws + WS_X1B);
            float mx = -INFINITY, mn = INFINITY;
            for (int k = 0; k < NN; ++k) {
                float v = x1[(b * NN + k) * NC + c];
                x1b[(b * NN + k) * NC + c] = f2b(v);
                mx = fmaxf(mx, v); mn = fminf(mn, v);
            }
            ws[WS_R1 + b * 2 * NC + 2 * c]     = mx;
            ws[WS_R1 + b * 2 * NC + 2 * c + 1] = mn;
        }
    } else {
        // red2: x2 -> bf16 + r2b (bf16 interleaved), 4 waves per (b,i)
        int idx = bb - 3082;
        int i = idx & 31, b = idx >> 5;
        int w = t >> 6, c = t & 63;
        unsigned short* x2b = (unsigned short*)(ws + WS_X2B);
        float mx = -INFINITY, mn = INFINITY;
        #pragma unroll
        for (int q = 0; q < 8; ++q) {
            int jj = w * 8 + q;
            float v = x2[((b * NN + i) * NN + jj) * NC + c];
            x2b[((b * NN + i) * NN + jj) * NC + c] = f2b(v);
            mx = fmaxf(mx, (jj == i) ? 0.0f : v);
            mn = fminf(mn, (jj == i) ? 1.0f : v);
        }
        pmx[w][c] = mx; pmn[w][c] = mn;
        __syncthreads();
        if (t < 64) {
            mx = fmaxf(fmaxf(pmx[0][c], pmx[1][c]), fmaxf(pmx[2][c], pmx[3][c]));
            mn = fminf(fminf(pmn[0][c], pmn[1][c]), fminf(pmn[2][c], pmn[3][c]));
            unsigned short* r2b = (unsigned short*)(ws + WS_R2B);
            unsigned int packed = (unsigned int)f2b(mx) | ((unsigned int)f2b(mn) << 16);
            *(unsigned int*)(r2b + (b * NN + i) * 128 + 2 * c) = packed;
        }
    }
}

// ---- o3 via MFMA, PAIRED, 8 waves: block = (b = blk&7 [XCD-affine], pi = blk>>3).
// wave wv = nt (0..3) x mh (0..1). Per wave: 24 A-frag reads, 48 MFMAs (I/J accs).
// A[32 k][768 K] bf16 LDS, XOR-swizzled (48 KB).
// __launch_bounds__(512, 4): 4 waves/EU = 2 blocks/CU (matches measured occupancy)
// -> VGPR cap 128 so the 48 in-loop weight loads can be register-pipelined
// (round-8 at VGPR=40 serialized on L2 latency every 2 MFMAs).
__global__ __launch_bounds__(512, 4) void out3k_pair(
        const float* __restrict__ x3, const float* __restrict__ ws_f,
        float* __restrict__ out) {
    __shared__ unsigned short A[32 * 768];   // 48 KB
    int blk = blockIdx.x;
    int b = blk & 7, pi = blk >> 3;   // XCD-affine: each XCD owns one batch b
    // triangular decode: largest i with C(i)=i*(65-i)/2 <= pi
    float fsq = sqrtf(4225.0f - 8.0f * (float)pi);
    int i = (int)((65.0f - fsq) * 0.5f);
    while (i > 0 && (i * (65 - i)) / 2 > pi) --i;
    while (((i + 1) * (64 - i)) / 2 <= pi) ++i;
    int j = i + (pi - (i * (65 - i)) / 2);

    int t = threadIdx.x;
    int lane = t & 63, wv = t >> 6;
    int nt = wv & 3, mh = wv >> 2;
    const unsigned short* x2b = (const unsigned short*)(ws_f + WS_X2B);
    const unsigned short* wc = (const unsigned short*)(ws_f + WS_WC);
    char* Ab = (char*)A;

    // ---- stage 12 tiles across all 512 threads ----
    {
        // x2b chunks: t<256 -> chunks 0-2, t>=256 -> chunks 3-5; 32 rows x 8 colgrps
        int r8 = (t >> 3) & 31, c8 = (t & 7) << 3;
        int cset = (t >> 8) * 3;
        size_t cb[6]; int cs[6];
        cb[0] = ((b * 32 + i) * 32 + j) * 64; cs[0] = 0;
        cb[1] = ((b * 32 + i) * 32) * 64;     cs[1] = 64;
        cb[2] = ((b * 32 + j) * 32 + i) * 64; cs[2] = 0;
        cb[3] = (b * 1024 + i) * 64;          cs[3] = 2048;
        cb[4] = ((b * 32 + j) * 32) * 64;     cs[4] = 64;
        cb[5] = (b * 1024 + j) * 64;          cs[5] = 2048;
        int sw = (r8 & 7) << 4;
        #pragma unroll
        for (int cc = 0; cc < 3; ++cc) {
            int ch = cset + cc;
            bf16x8 v = *(const bf16x8*)(x2b + cb[ch] + (size_t)r8 * cs[ch] + c8);
            *(bf16x8*)(Ab + ((r8 * 1536 + (ch * 64 + c8) * 2) ^ sw)) = v;
        }
        // x3 chunks: 32 rows (t>>4) x 16 colgrps (f32x4); each thread all 6 chunks
        int r32 = t >> 4, c4 = (t & 15) << 2;
        const float* xb[6]; int xs[6];
        xb[0] = x3 + (size_t)(((b * 32 + i) * 32 + j) * 32) * 64; xs[0] = 64;
        xb[1] = x3 + (size_t)(((b * 32 + i) * 32) * 32 + j) * 64; xs[1] = 2048;
        xb[2] = x3 + (size_t)(((b * 32 + j) * 32 + i) * 32) * 64; xs[2] = 64;
        xb[3] = x3 + (size_t)((b * 1024 + i) * 32 + j) * 64;      xs[3] = 65536;
        xb[4] = x3 + (size_t)(((b * 32 + j) * 32) * 32 + i) * 64; xs[4] = 2048;
        xb[5] = x3 + (size_t)(b * 32768 + j * 32 + i) * 64;       xs[5] = 65536;
        int sw2 = (r32 & 7) << 4;
        #pragma unroll
        for (int ch = 0; ch < 6; ++ch) {
            f32x4 v = *(const f32x4*)(xb[ch] + (size_t)r32 * xs[ch] + c4);
            u16x4 hh = { f2b(v[0]), f2b(v[1]), f2b(v[2]), f2b(v[3]) };
            *(u16x4*)(Ab + ((r32 * 1536 + ((6 + ch) * 64 + c4) * 2) ^ sw2)) = hh;
        }
    }
    __syncthreads();

    // ---- MFMA: per wave 24 A-reads feed 48 MFMAs (ij and ji accumulators) ----
    f32x4 accI = {0.f,0.f,0.f,0.f};   // (i,j) output, m-half mh
    f32x4 accJ = {0.f,0.f,0.f,0.f};   // (j,i) output, m-half mh
    const unsigned short* wblk = wc + (size_t)((b * 4 + nt) * 24) * 512 + lane * 8;
    int arow = (lane & 15) + mh * 16;
    int kgrp2 = ((lane >> 4) << 3) * 2;
    int sw0 = ((lane & 15) & 7) << 4;
    const int P1[12] = {2, 4, 0, 5, 1, 3, 8, 10, 6, 11, 7, 9};
    #pragma unroll
    for (int c = 0; c < 12; ++c) {
        #pragma unroll
        for (int s = 0; s < 2; ++s) {
            int colb = c * 128 + s * 64 + kgrp2;
            bf16x8 a = *(const bf16x8*)(Ab + ((arow * 1536 + colb) ^ sw0));
            bf16x8 w0 = *(const bf16x8*)(wblk + (2 * c + s) * 512);
            bf16x8 w1 = *(const bf16x8*)(wblk + (2 * P1[c] + s) * 512);
            accI = __builtin_amdgcn_mfma_f32_16x16x32_bf16(a, w0, accI, 0, 0, 0);
            accJ = __builtin_amdgcn_mfma_f32_16x16x32_bf16(a, w1, accJ, 0, 0, 0);
        }
    }

    // ---- fused r3b: wave0 from chunk6 -> (i,j); wave4 from chunk8 -> (j,i) ----
    if (wv == 0 || (wv == 4 && i != j)) {
        int c = lane;
        int colbase = (wv == 0) ? 384 : 512;   // chunk 6 / chunk 8 column base
        float mx = 0.0f, mn = 1.0f;            // masked entries contribute 0 / 1
        if (i != j) {
            for (int k = 0; k < 32; ++k) {
                if (k == i || k == j) continue;
                int addr = (k * 1536 + (colbase + c) * 2) ^ ((k & 7) << 4);
                float v = b2f(*(const unsigned short*)(Ab + addr));
                mx = fmaxf(mx, v); mn = fminf(mn, v);
            }
        }
        unsigned short* r3b = (unsigned short*)(ws_f + WS_R3B);
        int slot = (wv == 0) ? ((b * 32 + i) * 32 + j) : ((b * 32 + j) * 32 + i);
        unsigned int packed = (unsigned int)f2b(mx) | ((unsigned int)f2b(mn) << 16);
        *(unsigned int*)(r3b + (size_t)slot * 128 + 2 * c) = packed;
    }

    // ---- epilogue: rows mh*16 + (lane>>4)*4 + r ----
    float g3 = ws_f[WS_G + 3];
    int o = nt * 16 + (lane & 15);
    float bias = ws_f[WS_BB + b * 64 + o];
    int row0 = mh * 16 + ((lane >> 4) << 2);
    float* ob0 = out + (size_t)(((b * 32 + i) * 32 + j) * 32) * 64;
    float* ob1 = out + (size_t)(((b * 32 + j) * 32 + i) * 32) * 64;
    #pragma unroll
    for (int r = 0; r < 4; ++r) {
        float s0 = accI[r] + bias;
        ob0[(row0 + r) * 64 + o] = (g3 != 0.0f) ? sigmoidf_(s0) : 0.0f;
    }
    if (i != j) {
        #pragma unroll
        for (int r = 0; r < 4; ++r) {
            float s1 = accJ[r] + bias;
            ob1[(row0 + r) * 64 + o] = (g3 != 0.0f) ? sigmoidf_(s1) : 0.0f;
        }
    }
}

// ---- o0 + o1 fused: blocks 0..7 = o0 (t<64); blocks 8..15 = o1 MFMA ----
__global__ __launch_bounds__(256) void out01(
        const float* __restrict__ x0,
        const float* __restrict__ w_op0, const float* __restrict__ b_op0,
        const float* __restrict__ w_red0, const float* __restrict__ b_red0,
        const float* __restrict__ ws_f, float* __restrict__ out0,
        float* __restrict__ out1) {
    __shared__ unsigned short A[32 * 256];   // 16 KB (o1 path only)
    int bb = blockIdx.x, t = threadIdx.x;
    if (bb < 8) {
        if (t >= 64) return;
        int b = bb, o = t;
        float g  = ws_f[WS_G + 0];
        float m0 = ws_f[WS_MF + b * 10 + 0], m1 = ws_f[WS_MF + b * 10 + 1];
        float d0 = b_op0[o];
        for (int c = 0; c < NC; ++c) d0 += w_op0[o * NC + c] * x0[b * NC + c];
        float d1 = b_red0[o];
        for (int c = 0; c < 2 * NC; ++c) d1 += w_red0[o * 2 * NC + c] * ws_f[WS_R1 + b * 2 * NC + c];
        float s = m0 * d0 + m1 * d1;
        out0[b * NO + o] = (g != 0.0f) ? sigmoidf_(s) : 0.0f;
        return;
    }
    int b = bb - 8;
    int lane = t & 63, nt = t >> 6;
    const unsigned short* x0b = (const unsigned short*)(ws_f + WS_X0B);
    const unsigned short* x1b = (const unsigned short*)(ws_f + WS_X1B);
    const unsigned short* r2b = (const unsigned short*)(ws_f + WS_R2B);
    const unsigned short* wc1 = (const unsigned short*)(ws_f + WS_WC1);
    char* Ab = (char*)A;
    int r = t >> 3, c8 = (t & 7) << 3;
    int sw = (r & 7) << 4;
    {
        bf16x8 v0 = *(const bf16x8*)(x0b + b * 64 + c8);
        bf16x8 v1 = *(const bf16x8*)(x1b + (b * 32 + r) * 64 + c8);
        bf16x8 v2 = *(const bf16x8*)(r2b + (b * 32 + r) * 128 + c8);
        bf16x8 v3 = *(const bf16x8*)(r2b + (b * 32 + r) * 128 + 64 + c8);
        *(bf16x8*)(Ab + ((r * 512 + (0 * 64 + c8) * 2) ^ sw)) = v0;
        *(bf16x8*)(Ab + ((r * 512 + (1 * 64 + c8) * 2) ^ sw)) = v1;
        *(bf16x8*)(Ab + ((r * 512 + (2 * 64 + c8) * 2) ^ sw)) = v2;
        *(bf16x8*)(Ab + ((r * 512 + (3 * 64 + c8) * 2) ^ sw)) = v3;
    }
    __syncthreads();
    f32x4 acc0 = {0.f,0.f,0.f,0.f};
    f32x4 acc1 = {0.f,0.f,0.f,0.f};
    const unsigned short* wblk = wc1 + (size_t)((b * 4 + nt) * 8) * 512 + lane * 8;
    int arow0 = lane & 15, arow1 = 16 + arow0;
    int kgrp2 = ((lane >> 4) << 3) * 2;
    int sw0 = (arow0 & 7) << 4;
    #pragma unroll
    for (int kk = 0; kk < 8; ++kk) {
        int kloc2 = kk * 64 + kgrp2;
        bf16x8 a0 = *(const bf16x8*)(Ab + ((arow0 * 512 + kloc2) ^ sw0));
        bf16x8 a1 = *(const bf16x8*)(Ab + ((arow1 * 512 + kloc2) ^ sw0));
        bf16x8 bw = *(const bf16x8*)(wblk + kk * 512);
        acc0 = __builtin_amdgcn_mfma_f32_16x16x32_bf16(a0, bw, acc0, 0, 0, 0);
        acc1 = __builtin_amdgcn_mfma_f32_16x16x32_bf16(a1, bw, acc1, 0, 0, 0);
    }
    float g1 = ws_f[WS_G + 1];
    int o = nt * 16 + (lane & 15);
    float bias = ws_f[WS_BB1 + b * 64 + o];
    int rgrp = (lane >> 4) << 2;
    float* obase = out1 + b * 2048;
    #pragma unroll
    for (int rr = 0; rr < 4; ++rr) {
        float s0 = acc0[rr] + bias;
        float s1 = acc1[rr] + bias;
        obase[(rgrp + rr) * 64 + o]      = (g1 != 0.0f) ? sigmoidf_(s0) : 0.0f;
        obase[(16 + rgrp + rr) * 64 + o] = (g1 != 0.0f) ? sigmoidf_(s1) : 0.0f;
    }
}

// ---- o2 via MFMA: block per (b,i); A[32 j][512 K] bf16 LDS, XOR-swizzled ----
// __launch_bounds__(256, 4): VGPR cap 128 so the 32 in-loop weight loads pipeline.
__global__ __launch_bounds__(256, 4) void out2k_mfma(
        const float* __restrict__ ws_f, float* __restrict__ out) {
    __shared__ unsigned short A[32 * 512];   // 32 KB
    int blk = blockIdx.x;
    int i = blk & 31, b = blk >> 5;
    int t = threadIdx.x;
    int lane = t & 63, nt = t >> 6;
    const unsigned short* x1b = (const unsigned short*)(ws_f + WS_X1B);
    const unsigned short* x2b = (const unsigned short*)(ws_f + WS_X2B);
    const unsigned short* r3b = (const unsigned short*)(ws_f + WS_R3B);
    const unsigned short* wc2 = (const unsigned short*)(ws_f + WS_WC2);
    char* Ab = (char*)A;
    int r8 = t >> 3, c8 = (t & 7) << 3;
    {
        bf16x8 v0 = *(const bf16x8*)(x1b + (b * 32 + i) * 64 + c8);
        bf16x8 v1 = *(const bf16x8*)(x1b + b * 2048 + r8 * 64 + c8);
        bf16x8 v2 = *(const bf16x8*)(x2b + ((b * 32 + i) * 32) * 64 + r8 * 64 + c8);
        bf16x8 v3 = *(const bf16x8*)(x2b + (b * 1024 + i) * 64 + r8 * 2048 + c8);
        int sw = (r8 & 7) << 4;
        *(bf16x8*)(Ab + ((r8 * 1024 + (0 * 64 + c8) * 2) ^ sw)) = v0;
        *(bf16x8*)(Ab + ((r8 * 1024 + (1 * 64 + c8) * 2) ^ sw)) = v1;
        *(bf16x8*)(Ab + ((r8 * 1024 + (2 * 64 + c8) * 2) ^ sw)) = v2;
        *(bf16x8*)(Ab + ((r8 * 1024 + (3 * 64 + c8) * 2) ^ sw)) = v3;
    }
    int r16 = t >> 4, c16 = (t & 15) << 3;
    #pragma unroll
    for (int p = 0; p < 2; ++p) {
        int jr = p * 16 + r16;
        bf16x8 v4 = *(const bf16x8*)(r3b + ((b * 32 + i) * 32 + jr) * 128 + c16);
        bf16x8 v5 = *(const bf16x8*)(r3b + ((b * 32 + jr) * 32 + i) * 128 + c16);
        int sw = (jr & 7) << 4;
        *(bf16x8*)(Ab + ((jr * 1024 + (256 + c16) * 2) ^ sw)) = v4;
        *(bf16x8*)(Ab + ((jr * 1024 + (384 + c16) * 2) ^ sw)) = v5;
    }
    __syncthreads();
    f32x4 acc0 = {0.f,0.f,0.f,0.f};
    f32x4 acc1 = {0.f,0.f,0.f,0.f};
    const unsigned short* wblk = wc2 + (size_t)((b * 4 + nt) * 16) * 512 + lane * 8;
    int arow0 = lane & 15, arow1 = 16 + arow0;
    int kgrp2 = ((lane >> 4) << 3) * 2;
    int sw0 = (arow0 & 7) << 4;
    #pragma unroll
    for (int kk = 0; kk < 16; ++kk) {
        int kloc2 = kk * 64 + kgrp2;
        bf16x8 a0 = *(const bf16x8*)(Ab + ((arow0 * 1024 + kloc2) ^ sw0));
        bf16x8 a1 = *(const bf16x8*)(Ab + ((arow1 * 1024 + kloc2) ^ sw0));
        bf16x8 bf = *(const bf16x8*)(wblk + kk * 512);
        acc0 = __builtin_amdgcn_mfma_f32_16x16x32_bf16(a0, bf, acc0, 0, 0, 0);
        acc1 = __builtin_amdgcn_mfma_f32_16x16x32_bf16(a1, bf, acc1, 0, 0, 0);
    }
    float g2 = ws_f[WS_G + 2];
    int o = nt * 16 + (lane & 15);
    float bias = ws_f[WS_BB2 + b * 64 + o];
    int rgrp = (lane >> 4) << 2;
    float* obase = out + (size_t)((b * 32 + i) * 32) * 64;
    #pragma unroll
    for (int r = 0; r < 4; ++r) {
        float s0 = acc0[r] + bias;
        float s1 = acc1[r] + bias;
        obase[(rgrp + r) * 64 + o]      = (g2 != 0.0f) ? sigmoidf_(s0) : 0.0f;
        obase[(16 + rgrp + r) * 64 + o] = (g2 != 0.0f) ? sigmoidf_(s1) : 0.0f;
    }
}

extern "C" void kernel_launch(void* const* d_in, const int* in_sizes, int n_in,
                              void* d_out, int out_size, void* d_ws, size_t ws_size,
                              hipStream_t stream) {
    const float* x0 = (const float*)d_in[0];
    const float* x1 = (const float*)d_in[1];
    const float* x2 = (const float*)d_in[2];
    const float* x3 = (const float*)d_in[3];
    const float* w_op0 = (const float*)d_in[4];   const float* b_op0 = (const float*)d_in[5];
    const float* w_red0 = (const float*)d_in[6];  const float* b_red0 = (const float*)d_in[7];
    const float* w_exp1 = (const float*)d_in[8];  const float* b_exp1 = (const float*)d_in[9];
    const float* w_op1 = (const float*)d_in[10];  const float* b_op1 = (const float*)d_in[11];
    const float* w_red1 = (const float*)d_in[12]; const float* b_red1 = (const float*)d_in[13];
    const float* w_exp2 = (const float*)d_in[14]; const float* b_exp2 = (const float*)d_in[15];
    const float* w_op2 = (const float*)d_in[16];  const float* b_op2 = (const float*)d_in[17];
    const float* w_red2 = (const float*)d_in[18]; const float* b_red2 = (const float*)d_in[19];
    const float* w_exp3 = (const float*)d_in[20]; const float* b_exp3 = (const float*)d_in[21];
    const float* w_op3 = (const float*)d_in[22];  const float* b_op3 = (const float*)d_in[23];
    const int* act = (const int*)d_in[24];

    float* ws = (float*)d_ws;   // needs ~4.97 MB
    float* out = (float*)d_out;
    float* out0 = out;               // [0, 512)
    float* out1 = out + 512;         // [512, 16896)
    float* out2 = out + 16896;       // [16896, 541184)
    float* out3 = out + 541184;      // [541184, 17318400)

    prep_all<<<3338, 256, 0, stream>>>(x0, x1, x2,
                                       w_exp3, w_op3, w_exp2, w_op2, w_red2,
                                       w_exp1, w_op1, w_red1,
                                       b_exp1, b_op1, b_red1,
                                       b_exp2, b_op2, b_red2,
                                       b_exp3, b_op3, act, ws);
    out3k_pair<<<NB * 528, 512, 0, stream>>>(x3, ws, out3);
    out01<<<16, 256, 0, stream>>>(x0, w_op0, b_op0, w_red0, b_red0, ws, out0, out1);
    out2k_mfma<<<NB * NN, 256, 0, stream>>>(ws, out2);
}